// Round 12
// baseline (1184.001 us; speedup 1.0000x reference)
//
#include <hip/hip_runtime.h>
#include <math.h>

#define MQ 512           // states q
#define ML 512           // sequence length L
#define MS 26            // symbols
#define MB 32            // batch
#define MM 2             // models
#define NPOST (MM*MB*ML*MQ)   // 16777216

// ws layout (float slots)
#define OFF_A    0                               // MM*MQ*MQ fp32 prob A
#define OFF_AQ8  (OFF_A + MM*MQ*MQ)              // i8-packed A  [m][128 ip][512 j] dwords
#define OFF_ATQ8 (OFF_AQ8 + MM*128*MQ)           // i8-packed AT
#define OFF_CP   (OFF_ATQ8 + MM*128*MQ)          // col partial maxes [m][16][512]
#define OFF_ROWM (OFF_CP + MM*16*MQ)             // row maxes [m][512]
#define OFF_SCA  (OFF_ROWM + MM*MQ)              // 127/colmax
#define OFF_INVA (OFF_SCA + MM*MQ)               // colmax/127
#define OFF_SCT  (OFF_INVA + MM*MQ)              // 127/rowmax
#define OFF_INVT (OFF_SCT + MM*MQ)               // rowmax/127
#define OFF_B    (OFF_INVT + MM*MQ)
#define OFF_INIT (OFF_B + MM*MQ*MS)
#define OFF_E    (OFF_INIT + MM*MQ)
#define OFF_P1   (OFF_E + NPOST)
#define OFF_LL   (OFF_P1 + NPOST)

#if __has_builtin(__builtin_amdgcn_sdot4)
#define SDOT4(a,b,c) __builtin_amdgcn_sdot4((int)(a),(int)(b),(c),false)
#else
static __device__ __forceinline__ int SDOT4(unsigned a, unsigned b, int c){
  #pragma unroll
  for (int k=0;k<4;++k){
    int av = (int)((a >> (8*k)) & 0xffu); av = (av<<24)>>24;
    int bv = (int)((b >> (8*k)) & 0xffu); bv = (bv<<24)>>24;
    c += av*bv;
  }
  return c;
}
#endif

// ---------------- VALU cross-lane primitives (no LDS pipe) ----------------
#if __has_builtin(__builtin_amdgcn_mov_dpp)
#define DPPF(x, ctrl) __uint_as_float((unsigned)__builtin_amdgcn_mov_dpp(      \
    (int)__float_as_uint(x), (ctrl), 0xF, 0xF, true))
#define HAVE_DPP 1
#else
#define HAVE_DPP 0
#endif

#if __has_builtin(__builtin_amdgcn_permlane16_swap)
static __device__ __forceinline__ float pl16crossf(float x, int lane) {
    unsigned xi = __float_as_uint(x);
    auto r = __builtin_amdgcn_permlane16_swap(xi, xi, false, false);
    return __uint_as_float((lane & 16) ? r[0] : r[1]);
}
static __device__ __forceinline__ float pl16maxf(float x) {
    unsigned xi = __float_as_uint(x);
    auto r = __builtin_amdgcn_permlane16_swap(xi, xi, false, false);
    return fmaxf(__uint_as_float(r[0]), __uint_as_float(r[1]));
}
#else
static __device__ __forceinline__ float pl16crossf(float x, int lane) { (void)lane; return __shfl_xor(x, 16); }
static __device__ __forceinline__ float pl16maxf(float x) { return fmaxf(x, __shfl_xor(x, 16)); }
#endif

#if __has_builtin(__builtin_amdgcn_permlane32_swap)
static __device__ __forceinline__ float pl32crossf(float x, int lane) {
    unsigned xi = __float_as_uint(x);
    auto r = __builtin_amdgcn_permlane32_swap(xi, xi, false, false);
    return __uint_as_float((lane & 32) ? r[0] : r[1]);
}
static __device__ __forceinline__ float pl32maxf(float x) {
    unsigned xi = __float_as_uint(x);
    auto r = __builtin_amdgcn_permlane32_swap(xi, xi, false, false);
    return fmaxf(__uint_as_float(r[0]), __uint_as_float(r[1]));
}
#else
static __device__ __forceinline__ float pl32crossf(float x, int lane) { (void)lane; return __shfl_xor(x, 32); }
static __device__ __forceinline__ float pl32maxf(float x) { return fmaxf(x, __shfl_xor(x, 32)); }
#endif

#if HAVE_DPP
static __device__ __forceinline__ float ror8f(float x) { return DPPF(x, 0x128); }
// dual-chain full-wave max, stages interleaved (independent dep chains)
#define WAVEMAX2(XA, XB, MXA, MXB) do { float _a = (XA), _b = (XB);           \
  _a = fmaxf(_a, DPPF(_a, 0xB1));  _b = fmaxf(_b, DPPF(_b, 0xB1));           \
  _a = fmaxf(_a, DPPF(_a, 0x4E));  _b = fmaxf(_b, DPPF(_b, 0x4E));           \
  _a = fmaxf(_a, DPPF(_a, 0x124)); _b = fmaxf(_b, DPPF(_b, 0x124));          \
  _a = fmaxf(_a, DPPF(_a, 0x128)); _b = fmaxf(_b, DPPF(_b, 0x128));          \
  _a = pl16maxf(_a);               _b = pl16maxf(_b);                        \
  _a = pl32maxf(_a);               _b = pl32maxf(_b);                        \
  MXA = _a; MXB = _b; } while(0)
#define WAVEMAX(X, MX) do { float _m = (X);                                   \
  _m = fmaxf(_m, DPPF(_m, 0xB1));                                             \
  _m = fmaxf(_m, DPPF(_m, 0x4E));                                             \
  _m = fmaxf(_m, DPPF(_m, 0x124));                                            \
  _m = fmaxf(_m, DPPF(_m, 0x128));                                            \
  _m = pl16maxf(_m);                                                          \
  _m = pl32maxf(_m);                                                          \
  MX = _m; } while(0)
#else
static __device__ __forceinline__ float ror8f(float x) { return __shfl_xor(x, 8); }
#define WAVEMAX(X, MX) { MX = (X);                                            \
  _Pragma("unroll") for (int d = 1; d <= 32; d <<= 1)                         \
    MX = fmaxf(MX, __shfl_xor(MX, d)); }
#define WAVEMAX2(XA, XB, MXA, MXB) { WAVEMAX(XA, MXA); WAVEMAX(XB, MXB); }
#endif

// ---------------- row softmax of transition logits -> A (prob domain) ----------------
__global__ void k_softmaxA(const float* __restrict__ tl, float* __restrict__ A) {
    int row = blockIdx.x;                       // m*512 + i
    const float* x = tl + (size_t)row * MQ;
    float* y = A + (size_t)row * MQ;
    int tid = threadIdx.x;                      // 256 threads
    float v0 = x[tid], v1 = x[tid + 256];
    float mx = fmaxf(v0, v1);
    #pragma unroll
    for (int d = 32; d >= 1; d >>= 1) mx = fmaxf(mx, __shfl_xor(mx, d));
    __shared__ float sm[4], ss[4];
    int w = tid >> 6;
    if ((tid & 63) == 0) sm[w] = mx;
    __syncthreads();
    mx = fmaxf(fmaxf(sm[0], sm[1]), fmaxf(sm[2], sm[3]));
    float e0 = expf(v0 - mx), e1 = expf(v1 - mx);
    float s = e0 + e1;
    #pragma unroll
    for (int d = 32; d >= 1; d >>= 1) s += __shfl_xor(s, d);
    if ((tid & 63) == 0) ss[w] = s;
    __syncthreads();
    s = ss[0] + ss[1] + ss[2] + ss[3];
    float inv = 1.0f / s;
    y[tid] = e0 * inv;
    y[tid + 256] = e1 * inv;
}

// ---------------- column partial maxes + row maxes of A ----------------
__global__ void k_amaxc(const float* __restrict__ A, float* __restrict__ colpart,
                        float* __restrict__ rowmax) {
    int g = blockIdx.x, m = blockIdx.y;         // 16 x MM
    int tid = threadIdx.x;                      // 512
    const float* Am = A + (size_t)m*MQ*MQ;
    float cm = 0.f;
    for (int r = 0; r < 32; ++r)
        cm = fmaxf(cm, Am[(size_t)(g*32+r)*MQ + tid]);
    colpart[((size_t)m*16 + g)*MQ + tid] = cm;
    int w = tid >> 6, lane = tid & 63;
    for (int k = 0; k < 4; ++k) {
        int row = g*32 + w*4 + k;
        const float* rp = Am + (size_t)row*MQ;
        float rm = 0.f;
        #pragma unroll
        for (int c = 0; c < 8; ++c) rm = fmaxf(rm, rp[lane + 64*c]);
        #pragma unroll
        for (int d = 1; d <= 32; d <<= 1) rm = fmaxf(rm, __shfl_xor(rm, d));
        if (lane == 0) rowmax[m*MQ + row] = rm;
    }
}

// ---------------- finalize scales ----------------
__global__ void k_amaxr(const float* __restrict__ colpart, const float* __restrict__ rowmax,
                        float* __restrict__ scA, float* __restrict__ invA,
                        float* __restrict__ scT, float* __restrict__ invT) {
    int m = blockIdx.x, j = threadIdx.x;        // MM x 512
    float cm = 0.f;
    #pragma unroll
    for (int g = 0; g < 16; ++g) cm = fmaxf(cm, colpart[((size_t)m*16 + g)*MQ + j]);
    scA[m*MQ + j] = 127.f / cm;  invA[m*MQ + j] = cm * (1.f/127.f);
    float rm = rowmax[m*MQ + j];
    scT[m*MQ + j] = 127.f / rm;  invT[m*MQ + j] = rm * (1.f/127.f);
}

// ---------------- pack A -> i8 dwords [m][ip][j], per-column scale ----------------
__global__ void k_packA8(const float* __restrict__ A, const float* __restrict__ sc,
                         unsigned* __restrict__ Aq) {
    int ip = blockIdx.x, m = blockIdx.y, j = threadIdx.x;  // 128 x MM, 512 thr
    const float* Am = A + (size_t)m*MQ*MQ;
    float s = sc[m*MQ + j];
    unsigned d = 0;
    #pragma unroll
    for (int r = 0; r < 4; ++r) {
        int q = (int)(Am[(size_t)(4*ip+r)*MQ + j] * s + 0.5f);
        d |= ((unsigned)q & 0xffu) << (8*r);
    }
    Aq[((size_t)m*128 + ip)*MQ + j] = d;
}

// ---------------- pack AT -> i8 dwords via 64x64 tile, per-row-of-A scale ----------
__global__ void k_packAT8(const float* __restrict__ A, const float* __restrict__ scT,
                          unsigned* __restrict__ ATq) {
    __shared__ float tile[64][65];
    int ipb = blockIdx.x, jjb = blockIdx.y, m = blockIdx.z;  // 8 x 8 x MM
    int tx = threadIdx.x, ty = threadIdx.y;     // (64,4)
    const float* Am = A + (size_t)m*MQ*MQ;
    for (int r = ty; r < 64; r += 4)
        tile[r][tx] = Am[(size_t)(jjb*64 + r)*MQ + ipb*64 + tx];
    __syncthreads();
    float s = scT[m*MQ + jjb*64 + tx];
    for (int ipl = ty; ipl < 16; ipl += 4) {
        unsigned d = 0;
        #pragma unroll
        for (int r = 0; r < 4; ++r) {
            int q = (int)(tile[tx][4*ipl + r] * s + 0.5f);
            d |= ((unsigned)q & 0xffu) << (8*r);
        }
        ATq[((size_t)m*128 + ipb*16 + ipl)*MQ + jjb*64 + tx] = d;
    }
}

// ---------------- emission softmax (B) + init softmax ----------------
__global__ void k_bprep(const float* __restrict__ emis, const float* __restrict__ initl,
                        float* __restrict__ Bmat, float* __restrict__ initp) {
    int m = blockIdx.x;
    int q = threadIdx.x;                        // 512 threads
    const float* er = emis + ((size_t)(m*MQ) + q) * MS;
    float tv[MS];
    float mx = -1e30f;
    #pragma unroll
    for (int s = 0; s < MS; s++) { tv[s] = er[s]; mx = fmaxf(mx, tv[s]); }
    float sum = 0.f;
    #pragma unroll
    for (int s = 0; s < MS; s++) { tv[s] = expf(tv[s] - mx); sum += tv[s]; }
    float inv = 1.f / sum;
    float* bo = Bmat + ((size_t)(m*MQ) + q) * MS;
    #pragma unroll
    for (int s = 0; s < MS; s++) bo[s] = tv[s] * inv;

    __shared__ float red2[8];
    float v = initl[m*MQ + q];
    float mx2 = v;
    #pragma unroll
    for (int d = 32; d >= 1; d >>= 1) mx2 = fmaxf(mx2, __shfl_xor(mx2, d));
    if ((q & 63) == 0) red2[q >> 6] = mx2;
    __syncthreads();
    mx2 = red2[0];
    #pragma unroll
    for (int k = 1; k < 8; k++) mx2 = fmaxf(mx2, red2[k]);
    float e = expf(v - mx2);
    float s2 = e;
    #pragma unroll
    for (int d = 32; d >= 1; d >>= 1) s2 += __shfl_xor(s2, d);
    __syncthreads();
    if ((q & 63) == 0) red2[q >> 6] = s2;
    __syncthreads();
    s2 = 0.f;
    #pragma unroll
    for (int k = 0; k < 8; k++) s2 += red2[k];
    initp[m*MQ + q] = e / s2;
}

// ---------------- E[m,b,l,q] = sum_s inputs[m,b,l,s]*B[m,q,s] + EPS ----------------
__global__ void k_ekernel(const float* __restrict__ inp, const float* __restrict__ Bmat,
                          float* __restrict__ E) {
    int lc = blockIdx.x, b = blockIdx.y, m = blockIdx.z;
    int tid = threadIdx.x;                      // 512
    __shared__ float Bl[MQ * MS];               // 53KB
    __shared__ float xl[8 * MS];
    for (int k = tid; k < MQ * MS; k += 512) Bl[k] = Bmat[(size_t)m * MQ * MS + k];
    int l0 = lc * 8;
    const float* xin = inp + (((size_t)(m*MB + b) * ML + l0) * MS);
    for (int k = tid; k < 8 * MS; k += 512) xl[k] = xin[k];
    __syncthreads();
    float* Eo = E + (((size_t)(m*MB + b) * ML + l0) * MQ);
    const float* br = Bl + tid * MS;
    for (int l = 0; l < 8; l++) {
        float acc = 1e-16f;
        const float* xr = xl + l * MS;
        #pragma unroll
        for (int s = 0; s < MS; s++) acc = fmaf(br[s], xr[s], acc);
        Eo[l * MQ + tid] = acc;
    }
}

// ---------------- fused fwd/bwd: 64 blocks (dir,m,bpair) x 512 threads, i8 dots ------
// R12 = R10 resubmit with defensive macro-parameter renames (WAVEMAX2's old MXB
// param collided with the MB object macro -- legal but renamed).  Dual-chain
// (R5 macro-structure) + R8 improvements + EXPLICIT source-level interleaving.
// Measured decomposition: T_step = T_fixed(1120cy) + k*T_chain(1630cy = 1080 busy +
// 550 stall).  Two chains amortize T_fixed; interleaving the two chains'
// instruction streams lets chain B's busy fill chain A's stall -- which R5's
// sequential MATVECs provably failed to do (zero overlap).  Ar shared (same m,dir).
// One lgkm-only barrier; post-barrier stores; Mig-derived c.

#define SHM_DYN 81920               // big dyn-LDS pins 1 block/CU

// LDS byte offsets: chain c in {0,1}, buffer buf in {0,1}
#define CAB(c,buf)  ((c)*2048 + (buf)*640)          // 8 slots x 80B alpha bytes
#define CSM(c,buf)  ((c)*2048 + 1280 + (buf)*32)    // 8 wave maxes (f32)
#define REDB  4096                                  // loglik scratch: 2 x 8 f32

static __device__ __forceinline__ float fastrcp(float x) {
    float r;
    asm("v_rcp_f32 %0, %1" : "=v"(r) : "v"(x));
    return r;
}

#define DOTA(P, AD) { ua[0]=SDOT4(Ar[(P)*2+0].x,(AD),ua[0]); ua[1]=SDOT4(Ar[(P)*2+0].y,(AD),ua[1]); \
  ua[2]=SDOT4(Ar[(P)*2+0].z,(AD),ua[2]); ua[3]=SDOT4(Ar[(P)*2+0].w,(AD),ua[3]);                     \
  ua[4]=SDOT4(Ar[(P)*2+1].x,(AD),ua[4]); ua[5]=SDOT4(Ar[(P)*2+1].y,(AD),ua[5]);                     \
  ua[6]=SDOT4(Ar[(P)*2+1].z,(AD),ua[6]); ua[7]=SDOT4(Ar[(P)*2+1].w,(AD),ua[7]); }
#define DOTB(P, AD) { ub[0]=SDOT4(Ar[(P)*2+0].x,(AD),ub[0]); ub[1]=SDOT4(Ar[(P)*2+0].y,(AD),ub[1]); \
  ub[2]=SDOT4(Ar[(P)*2+0].z,(AD),ub[2]); ub[3]=SDOT4(Ar[(P)*2+0].w,(AD),ub[3]);                     \
  ub[4]=SDOT4(Ar[(P)*2+1].x,(AD),ub[4]); ub[5]=SDOT4(Ar[(P)*2+1].y,(AD),ub[5]);                     \
  ub[6]=SDOT4(Ar[(P)*2+1].z,(AD),ub[6]); ub[7]=SDOT4(Ar[(P)*2+1].w,(AD),ub[7]); }

// dual-chain i8 matvec: both chains' LDS reads issued upfront, SDOT octets
// alternate A/B, butterfly stages pairwise interleaved.
#define MATVEC_DUAL(MVA, MVB, RDOFA, RDOFB, MIGA, MIGB) do {                  \
  int ua[8], ub[8];                                                           \
  _Pragma("unroll") for (int k=0;k<8;k++) { ua[k]=0; ub[k]=0; }               \
  const uint4* pa4 = (const uint4*)(abm + (RDOFA) + ig*80);                   \
  const uint4* pb4 = (const uint4*)(abm + (RDOFB) + ig*80);                   \
  uint4 pa0 = pa4[0], pa1 = pa4[1], pa2 = pa4[2], pa3 = pa4[3];               \
  uint4 pb0 = pb4[0], pb1 = pb4[1], pb2 = pb4[2], pb3 = pb4[3];               \
  DOTA(0,  pa0.x) DOTB(0,  pb0.x) DOTA(1,  pa0.y) DOTB(1,  pb0.y)             \
  DOTA(2,  pa0.z) DOTB(2,  pb0.z) DOTA(3,  pa0.w) DOTB(3,  pb0.w)             \
  DOTA(4,  pa1.x) DOTB(4,  pb1.x) DOTA(5,  pa1.y) DOTB(5,  pb1.y)             \
  DOTA(6,  pa1.z) DOTB(6,  pb1.z) DOTA(7,  pa1.w) DOTB(7,  pb1.w)             \
  DOTA(8,  pa2.x) DOTB(8,  pb2.x) DOTA(9,  pa2.y) DOTB(9,  pb2.y)             \
  DOTA(10, pa2.z) DOTB(10, pb2.z) DOTA(11, pa2.w) DOTB(11, pb2.w)             \
  DOTA(12, pa3.x) DOTB(12, pb3.x) DOTA(13, pa3.y) DOTB(13, pb3.y)             \
  DOTA(14, pa3.z) DOTB(14, pb3.z) DOTA(15, pa3.w) DOTB(15, pb3.w)             \
  float fua[8], fub[8];                                                       \
  _Pragma("unroll") for (int k=0;k<8;k++) {                                   \
    fua[k] = (float)ua[k] * (MIGA); fub[k] = (float)ub[k] * (MIGB); }         \
  const int h1 = ig & 1, h2 = (ig >> 1) & 1, h4 = (ig >> 2) & 1;              \
  float wa4[4], wb4[4];                                                       \
  _Pragma("unroll") for (int k=0;k<4;k++){                                    \
    float mia = h1 ? fua[2*k+1] : fua[2*k];                                   \
    float ota = h1 ? fua[2*k]   : fua[2*k+1];                                 \
    float mib = h1 ? fub[2*k+1] : fub[2*k];                                   \
    float otb = h1 ? fub[2*k]   : fub[2*k+1];                                 \
    wa4[k] = mia + ror8f(ota); wb4[k] = mib + ror8f(otb); }                   \
  float wa2[2], wb2[2];                                                       \
  _Pragma("unroll") for (int k=0;k<2;k++){                                    \
    float mia = h2 ? wa4[2*k+1] : wa4[2*k];                                   \
    float ota = h2 ? wa4[2*k]   : wa4[2*k+1];                                 \
    float mib = h2 ? wb4[2*k+1] : wb4[2*k];                                   \
    float otb = h2 ? wb4[2*k]   : wb4[2*k+1];                                 \
    wa2[k] = mia + pl16crossf(ota, lane); wb2[k] = mib + pl16crossf(otb, lane); } \
  { float mia = h4 ? wa2[1] : wa2[0];                                         \
    float ota = h4 ? wa2[0] : wa2[1];                                         \
    float mib = h4 ? wb2[1] : wb2[0];                                         \
    float otb = h4 ? wb2[0] : wb2[1];                                         \
    MVA = mia + pl32crossf(ota, lane); MVB = mib + pl32crossf(otb, lane); }   \
} while(0)

// lgkmcnt-only barrier: LDS writes visible, global stores NOT drained
#define STEP_BARRIER() asm volatile("s_waitcnt lgkmcnt(0)\n\ts_barrier" ::: "memory")

// dual forward step; RB/WB are compile-time 0/1 buffer ids
#define FSTEP2(T, RB, WB) do {                                                \
    float eva = evna, evb = evnb;                                             \
    int tn = ((T)+1 < ML) ? (T)+1 : ML-1;                                     \
    evna = Eb0[(size_t)tn*MQ + jown];                                         \
    evnb = Eb1[(size_t)tn*MQ + jown];                                         \
    float MigA = *(const float*)(abm + CSM(0,RB) + ig*4);                     \
    float MigB = *(const float*)(abm + CSM(1,RB) + ig*4);                     \
    float bfa, bfb; MATVEC_DUAL(bfa, bfb, CAB(0,RB), CAB(1,RB), MigA, MigB);  \
    float ca = MigA, cb = MigB;                                               \
    ca = fmaxf(ca, ror8f(ca)); cb = fmaxf(cb, ror8f(cb));                     \
    ca = pl16maxf(ca);         cb = pl16maxf(cb);                             \
    ca = pl32maxf(ca);         cb = pl32maxf(cb);                             \
    float invca = fastrcp(ca), invcb = fastrcp(cb);                           \
    Cc0 += __logf(ca); Cc1 += __logf(cb);                                     \
    float mva = bfa * (rsj126 * invca), mvb = bfb * (rsj126 * invcb);         \
    float fA = mva * eva, fB = mvb * evb;                                     \
    float Ma, Mb; WAVEMAX2(fA, fB, Ma, Mb);                                   \
    float qsa = 126.f * fastrcp(Ma), qsb = 126.f * fastrcp(Mb);               \
    abm[CAB(0,WB) + wslot] = (unsigned char)(int)(fA*qsa + 0.5f);             \
    abm[CAB(1,WB) + wslot] = (unsigned char)(int)(fB*qsb + 0.5f);             \
    if (lane == 0) { *(float*)(abm + CSM(0,WB) + w*4) = Ma;                   \
                     *(float*)(abm + CSM(1,WB) + w*4) = Mb; }                 \
    STEP_BARRIER();                                                           \
    P1[eb0 + (size_t)(T)*MQ + jown] = __logf(fA) + Cc0;                       \
    P1[eb1 + (size_t)(T)*MQ + jown] = __logf(fB) + Cc1;                       \
    fla = fA; flb = fB;                                                       \
} while(0)

// dual backward step
#define BSTEP2(T, RB, WB) do {                                                \
    float eva = evna, evb = evnb;                                             \
    int tn = ((T) > 0) ? (T)-1 : 0;                                           \
    evna = Eb0[(size_t)tn*MQ + jown];                                         \
    evnb = Eb1[(size_t)tn*MQ + jown];                                         \
    float MigA = *(const float*)(abm + CSM(0,RB) + ig*4);                     \
    float MigB = *(const float*)(abm + CSM(1,RB) + ig*4);                     \
    float bfa, bfb; MATVEC_DUAL(bfa, bfb, CAB(0,RB), CAB(1,RB), MigA, MigB);  \
    float ca = MigA, cb = MigB;                                               \
    ca = fmaxf(ca, ror8f(ca)); cb = fmaxf(cb, ror8f(cb));                     \
    ca = pl16maxf(ca);         cb = pl16maxf(cb);                             \
    ca = pl32maxf(ca);         cb = pl32maxf(cb);                             \
    float invca = fastrcp(ca), invcb = fastrcp(cb);                           \
    Dc0 += __logf(ca); Dc1 += __logf(cb);                                     \
    float mva = bfa * (rsj126 * invca), mvb = bfb * (rsj126 * invcb);         \
    float ya = mva * eva, yb = mvb * evb;                                     \
    float Ma, Mb; WAVEMAX2(ya, yb, Ma, Mb);                                   \
    float qsa = 126.f * fastrcp(Ma), qsb = 126.f * fastrcp(Mb);               \
    abm[CAB(0,WB) + wslot] = (unsigned char)(int)(ya*qsa + 0.5f);             \
    abm[CAB(1,WB) + wslot] = (unsigned char)(int)(yb*qsb + 0.5f);             \
    if (lane == 0) { *(float*)(abm + CSM(0,WB) + w*4) = Ma;                   \
                     *(float*)(abm + CSM(1,WB) + w*4) = Mb; }                 \
    STEP_BARRIER();                                                           \
    out[eb0 + (size_t)(T)*MQ + jown] = __logf(mva) + Dc0;                     \
    out[eb1 + (size_t)(T)*MQ + jown] = __logf(mvb) + Dc1;                     \
} while(0)

__global__ __launch_bounds__(512, 1) void k_fwdbwd(
    const unsigned* __restrict__ Aq8, const unsigned* __restrict__ ATq8,
    const float* __restrict__ invA, const float* __restrict__ invT,
    const float* __restrict__ E, const float* __restrict__ initp,
    float* __restrict__ P1, float* __restrict__ out, float* __restrict__ llws)
{
    extern __shared__ __align__(16) unsigned shm[];
    unsigned char* abm = (unsigned char*)shm;
    const int bid = blockIdx.x;                 // 64 blocks
    const int dir = bid & 1, m = (bid >> 1) & 1;
    const int b0 = (bid >> 2) * 2, b1 = b0 + 1; // chain pair
    const int tid = threadIdx.x;
    const int w = tid >> 6, lane = tid & 63;
    const int ig = lane >> 3, jg = lane & 7;
    const int jbase = w*64 + jg*8;
    const int jown = jbase + ig;
    const int wslot = (jown>>6)*80 + (jown&63); // byte pos of lane's alpha slot

    const unsigned* gQ = (dir ? ATq8 : Aq8) + (size_t)m * (128*MQ);
    const uint4* gQ4 = (const uint4*)gQ;
    const float rsj126 = (dir ? invT : invA)[m*MQ + jown] * (1.f/126.f);
    const size_t eb0 = ((size_t)(m*MB + b0)) * ML * MQ;
    const size_t eb1 = ((size_t)(m*MB + b1)) * ML * MQ;
    const float* Eb0 = E + eb0;
    const float* Eb1 = E + eb1;

    // ---- preload i8 A-slice (shared by both chains): 32 uint4 = 128 regs ----
    uint4 Ar[32];
    #pragma unroll
    for (int p = 0; p < 16; ++p) {
        Ar[p*2+0] = gQ4[(size_t)(ig*16 + p)*128 + (jbase>>2)];
        Ar[p*2+1] = gQ4[(size_t)(ig*16 + p)*128 + (jbase>>2) + 1];
    }

    if (dir == 0) {
        // ================= forward (2 chains, interleaved) =================
        float Cc0 = 0.f, Cc1 = 0.f;
        float fla, flb;
        {   // t = 0
            float eva = Eb0[jown], evb = Eb1[jown];
            float ipv = initp[m*MQ + jown];
            float fA = ipv * eva, fB = ipv * evb;
            float Ma, Mb; WAVEMAX2(fA, fB, Ma, Mb);
            float qsa = 126.f * fastrcp(Ma), qsb = 126.f * fastrcp(Mb);
            abm[CAB(0,0) + wslot] = (unsigned char)(int)(fA*qsa + 0.5f);
            abm[CAB(1,0) + wslot] = (unsigned char)(int)(fB*qsb + 0.5f);
            if (lane == 0) { *(float*)(abm + CSM(0,0) + w*4) = Ma;
                             *(float*)(abm + CSM(1,0) + w*4) = Mb; }
            P1[eb0 + jown] = __logf(fA);
            P1[eb1 + jown] = __logf(fB);
            fla = fA; flb = fB;
            STEP_BARRIER();
        }
        float evna = Eb0[MQ + jown], evnb = Eb1[MQ + jown];
        FSTEP2(1, 0, 1);
        #pragma unroll 1
        for (int t = 2; t < ML; t += 2) {
            FSTEP2(t,   1, 0);
            FSTEP2(t+1, 0, 1);
        }
        // loglik both chains
        float sa = fla, sb = flb;
        #pragma unroll
        for (int d = 1; d <= 32; d <<= 1) { sa += __shfl_xor(sa, d); sb += __shfl_xor(sb, d); }
        if (lane == 0) { *(float*)(abm + REDB + w*4) = sa;
                         *(float*)(abm + REDB + 32 + w*4) = sb; }
        __syncthreads();
        if (tid == 0) {
            float ta = 0.f, tb = 0.f;
            #pragma unroll
            for (int k = 0; k < 8; ++k) { ta += *(float*)(abm + REDB + k*4);
                                          tb += *(float*)(abm + REDB + 32 + k*4); }
            float lla = __logf(ta) + Cc0, llb = __logf(tb) + Cc1;
            llws[m*MB + b0] = lla;  out[NPOST + m*MB + b0] = lla;
            llws[m*MB + b1] = llb;  out[NPOST + m*MB + b1] = llb;
        }
    } else {
        // ================= backward (2 chains, interleaved) =================
        float Dc0 = 0.f, Dc1 = 0.f;
        {   // t = L-1
            float eva = Eb0[(size_t)(ML-1)*MQ + jown];
            float evb = Eb1[(size_t)(ML-1)*MQ + jown];
            float Ma, Mb; WAVEMAX2(eva, evb, Ma, Mb);
            float qsa = 126.f * fastrcp(Ma), qsb = 126.f * fastrcp(Mb);
            abm[CAB(0,0) + wslot] = (unsigned char)(int)(eva*qsa + 0.5f);
            abm[CAB(1,0) + wslot] = (unsigned char)(int)(evb*qsb + 0.5f);
            if (lane == 0) { *(float*)(abm + CSM(0,0) + w*4) = Ma;
                             *(float*)(abm + CSM(1,0) + w*4) = Mb; }
            out[eb0 + (size_t)(ML-1)*MQ + jown] = 0.f;
            out[eb1 + (size_t)(ML-1)*MQ + jown] = 0.f;
            STEP_BARRIER();
        }
        float evna = Eb0[(size_t)(ML-2)*MQ + jown];
        float evnb = Eb1[(size_t)(ML-2)*MQ + jown];
        BSTEP2(ML-2, 0, 1);
        #pragma unroll 1
        for (int t = ML-3; t >= 1; t -= 2) {
            BSTEP2(t,   1, 0);
            BSTEP2(t-1, 0, 1);
        }
    }
}

// ---------------- combine: out = P2(out) + P1 - loglik ----------------
__global__ void k_combine(const float* __restrict__ P1, const float* __restrict__ llws,
                          float* __restrict__ out) {
    size_t idx = ((size_t)blockIdx.x * 256 + threadIdx.x) * 4;
    int mb = (int)(idx >> 18);                  // L*Q = 262144 per (m,b)
    float ll = llws[mb];
    float4 p = *(const float4*)(P1 + idx);
    float4 o = *(const float4*)(out + idx);
    o.x = o.x + p.x - ll;
    o.y = o.y + p.y - ll;
    o.z = o.z + p.z - ll;
    o.w = o.w + p.w - ll;
    *(float4*)(out + idx) = o;
}

extern "C" void kernel_launch(void* const* d_in, const int* in_sizes, int n_in,
                              void* d_out, int out_size, void* d_ws, size_t ws_size,
                              hipStream_t stream) {
    (void)in_sizes; (void)n_in; (void)out_size; (void)ws_size;
    const float* inp   = (const float*)d_in[0];
    const float* trans = (const float*)d_in[1];
    const float* emis  = (const float*)d_in[2];
    const float* initl = (const float*)d_in[3];
    float* out = (float*)d_out;
    float* ws  = (float*)d_ws;

    float*    wsA    = ws + OFF_A;
    unsigned* wsAQ8  = (unsigned*)(ws + OFF_AQ8);
    unsigned* wsATQ8 = (unsigned*)(ws + OFF_ATQ8);
    float*    wsCP   = ws + OFF_CP;
    float*    wsROWM = ws + OFF_ROWM;
    float*    wsSCA  = ws + OFF_SCA;
    float*    wsINVA = ws + OFF_INVA;
    float*    wsSCT  = ws + OFF_SCT;
    float*    wsINVT = ws + OFF_INVT;
    float*    wsB    = ws + OFF_B;
    float*    wsInit = ws + OFF_INIT;
    float*    wsE    = ws + OFF_E;
    float*    wsP1   = ws + OFF_P1;
    float*    wsLL   = ws + OFF_LL;

    (void)hipFuncSetAttribute((const void*)k_fwdbwd,
                              hipFuncAttributeMaxDynamicSharedMemorySize,
                              SHM_DYN);

    k_softmaxA<<<MM*MQ, 256, 0, stream>>>(trans, wsA);
    k_amaxc<<<dim3(16, MM), 512, 0, stream>>>(wsA, wsCP, wsROWM);
    k_amaxr<<<MM, 512, 0, stream>>>(wsCP, wsROWM, wsSCA, wsINVA, wsSCT, wsINVT);
    k_packA8<<<dim3(128, MM), 512, 0, stream>>>(wsA, wsSCA, wsAQ8);
    k_packAT8<<<dim3(8, 8, MM), dim3(64, 4), 0, stream>>>(wsA, wsSCT, wsATQ8);
    k_bprep<<<MM, 512, 0, stream>>>(emis, initl, wsB, wsInit);
    k_ekernel<<<dim3(ML/8, MB, MM), 512, 0, stream>>>(inp, wsB, wsE);
    k_fwdbwd<<<64, 512, SHM_DYN, stream>>>(wsAQ8, wsATQ8, wsINVA, wsINVT,
                                           wsE, wsInit, wsP1, out, wsLL);
    k_combine<<<NPOST/1024, 256, 0, stream>>>(wsP1, wsLL, out);
}